// Round 1
// baseline (3447.334 us; speedup 1.0000x reference)
//
#include <hip/hip_runtime.h>

#define NN 40000
#define NE 640000
#define D  128

// ---------------- scatter: agg[dst] += h[src], h is [NN][128] ----------------
__global__ __launch_bounds__(256) void scatter_kernel(
    const float* __restrict__ h, const int* __restrict__ src,
    const int* __restrict__ dst, float* __restrict__ agg)
{
    int idx = blockIdx.x * 256 + threadIdx.x;
    int e = idx >> 5;            // 32 lanes per edge
    if (e >= NE) return;
    int lane = idx & 31;
    int s = src[e], d = dst[e];
    float4 v = reinterpret_cast<const float4*>(h)[(size_t)s * 32 + lane];
    float* o = agg + (size_t)d * D + lane * 4;
    atomicAdd(o + 0, v.x);
    atomicAdd(o + 1, v.y);
    atomicAdd(o + 2, v.z);
    atomicAdd(o + 3, v.w);
}

// ------- out = act(agg @ Wrel + h @ Wroot + b); M x 128, K = 128 ------------
template<bool RELU>
__global__ __launch_bounds__(256) void conv_gemm(
    const float* __restrict__ A,    // agg [M][128]
    const float* __restrict__ H,    // h   [M][128]
    const float* __restrict__ Wr,   // [128][128]
    const float* __restrict__ Wo,   // [128][128]
    const float* __restrict__ bias, // [128]
    float* __restrict__ out, int M)
{
    __shared__ float As[64][36];
    __shared__ float Hs[64][36];
    __shared__ float Wrs[32][128];
    __shared__ float Wos[32][128];

    const int tid  = threadIdx.x;
    const int row0 = blockIdx.x * 64;
    const int rg   = tid >> 4;   // 0..15 -> rows rg*4 .. rg*4+3
    const int cg   = tid & 15;   // 0..15 -> cols cg*8 .. cg*8+7

    float acc[4][8];
    #pragma unroll
    for (int i = 0; i < 4; i++)
        #pragma unroll
        for (int j = 0; j < 8; j++) acc[i][j] = 0.f;

    for (int k0 = 0; k0 < 128; k0 += 32) {
        // stage A,H tiles: 64 rows x 32 k, 512 float4 each -> 2 per thread
        #pragma unroll
        for (int l = 0; l < 2; l++) {
            int lin = tid + l * 256;       // 0..511
            int r   = lin >> 3;            // 0..63
            int f4  = lin & 7;             // 0..7
            float4 va = *reinterpret_cast<const float4*>(&A[(size_t)(row0 + r) * D + k0 + f4 * 4]);
            float4 vh = *reinterpret_cast<const float4*>(&H[(size_t)(row0 + r) * D + k0 + f4 * 4]);
            *reinterpret_cast<float4*>(&As[r][f4 * 4]) = va;
            *reinterpret_cast<float4*>(&Hs[r][f4 * 4]) = vh;
        }
        // stage W tiles: 32 k x 128, 1024 float4 each -> 4 per thread
        #pragma unroll
        for (int l = 0; l < 4; l++) {
            int lin = tid + l * 256;       // 0..1023
            int kk  = lin >> 5;            // 0..31
            int f4  = lin & 31;            // 0..31
            *reinterpret_cast<float4*>(&Wrs[kk][f4 * 4]) =
                *reinterpret_cast<const float4*>(&Wr[(size_t)(k0 + kk) * D + f4 * 4]);
            *reinterpret_cast<float4*>(&Wos[kk][f4 * 4]) =
                *reinterpret_cast<const float4*>(&Wo[(size_t)(k0 + kk) * D + f4 * 4]);
        }
        __syncthreads();

        #pragma unroll 8
        for (int kk = 0; kk < 32; kk++) {
            float a[4], hh[4];
            #pragma unroll
            for (int i = 0; i < 4; i++) { a[i] = As[rg * 4 + i][kk]; hh[i] = Hs[rg * 4 + i][kk]; }
            float4 wr0 = *reinterpret_cast<float4*>(&Wrs[kk][cg * 8]);
            float4 wr1 = *reinterpret_cast<float4*>(&Wrs[kk][cg * 8 + 4]);
            float4 wo0 = *reinterpret_cast<float4*>(&Wos[kk][cg * 8]);
            float4 wo1 = *reinterpret_cast<float4*>(&Wos[kk][cg * 8 + 4]);
            float wr[8] = {wr0.x, wr0.y, wr0.z, wr0.w, wr1.x, wr1.y, wr1.z, wr1.w};
            float wo[8] = {wo0.x, wo0.y, wo0.z, wo0.w, wo1.x, wo1.y, wo1.z, wo1.w};
            #pragma unroll
            for (int i = 0; i < 4; i++)
                #pragma unroll
                for (int j = 0; j < 8; j++)
                    acc[i][j] += a[i] * wr[j] + hh[i] * wo[j];
        }
        __syncthreads();
    }

    // epilogue: bias (+relu), float4 stores
    #pragma unroll
    for (int i = 0; i < 4; i++) {
        int r = row0 + rg * 4 + i;
        float o[8];
        #pragma unroll
        for (int j = 0; j < 8; j++) {
            float v = acc[i][j] + bias[cg * 8 + j];
            if (RELU) v = fmaxf(v, 0.f);
            o[j] = v;
        }
        float4* dst4 = reinterpret_cast<float4*>(&out[(size_t)r * D + cg * 8]);
        dst4[0] = make_float4(o[0], o[1], o[2], o[3]);
        dst4[1] = make_float4(o[4], o[5], o[6], o[7]);
    }
}

// ---------------- fc0: out[NN][64] = relu(h[NN][128] @ W[128][64] + b) ------
__global__ __launch_bounds__(256) void fc0_kernel(
    const float* __restrict__ h, const float* __restrict__ W,
    const float* __restrict__ bias, float* __restrict__ out)
{
    __shared__ float Ws[128][64];
    __shared__ float Hs[16][128];
    const int tid = threadIdx.x;
    const float4* W4 = reinterpret_cast<const float4*>(W);
    float4* Ws4 = reinterpret_cast<float4*>(&Ws[0][0]);
    #pragma unroll
    for (int l = 0; l < 8; l++) Ws4[tid + l * 256] = W4[tid + l * 256];
    const int row0 = blockIdx.x * 16;
    const float4* h4 = reinterpret_cast<const float4*>(h + (size_t)row0 * 128);
    float4* Hs4 = reinterpret_cast<float4*>(&Hs[0][0]);
    #pragma unroll
    for (int l = 0; l < 2; l++) Hs4[tid + l * 256] = h4[tid + l * 256];
    __syncthreads();

    const int wv  = tid >> 6;     // wave 0..3 -> rows wv*4 .. wv*4+3
    const int col = tid & 63;
    float acc[4] = {bias[col], bias[col], bias[col], bias[col]};
    #pragma unroll 4
    for (int k = 0; k < 128; k++) {
        float w = Ws[k][col];
        #pragma unroll
        for (int j = 0; j < 4; j++) acc[j] += Hs[wv * 4 + j][k] * w;
    }
    #pragma unroll
    for (int j = 0; j < 4; j++)
        out[(size_t)(row0 + wv * 4 + j) * 64 + col] = fmaxf(acc[j], 0.f);
}

// ---------------- fc1: out[NN] = h[NN][64] @ W[64] + b ----------------------
__global__ __launch_bounds__(256) void fc1_kernel(
    const float* __restrict__ h, const float* __restrict__ W,
    const float* __restrict__ bias, float* __restrict__ out)
{
    int row  = blockIdx.x * 4 + (threadIdx.x >> 6);
    int lane = threadIdx.x & 63;
    float v = h[(size_t)row * 64 + lane] * W[lane];
    #pragma unroll
    for (int off = 32; off > 0; off >>= 1) v += __shfl_down(v, off, 64);
    if (lane == 0) out[row] = v + bias[0];
}

extern "C" void kernel_launch(void* const* d_in, const int* in_sizes, int n_in,
                              void* d_out, int out_size, void* d_ws, size_t ws_size,
                              hipStream_t stream)
{
    const float* x    = (const float*)d_in[0];
    const int*   ei   = (const int*)d_in[1];
    const int*   src  = ei;
    const int*   dst  = ei + NE;
    const float* Wrel[3]  = {(const float*)d_in[2], (const float*)d_in[5], (const float*)d_in[8]};
    const float* Wroot[3] = {(const float*)d_in[3], (const float*)d_in[6], (const float*)d_in[9]};
    const float* bb[3]    = {(const float*)d_in[4], (const float*)d_in[7], (const float*)d_in[10]};
    const float* Wfc0 = (const float*)d_in[11];
    const float* bfc0 = (const float*)d_in[12];
    const float* Wfc1 = (const float*)d_in[13];
    const float* bfc1 = (const float*)d_in[14];
    float* out = (float*)d_out;

    float* P0 = (float*)d_ws;               // agg scratch
    float* P1 = P0 + (size_t)NN * D;
    float* P2 = P1 + (size_t)NN * D;

    const size_t hbytes = (size_t)NN * D * sizeof(float);
    dim3 sgrid((NE * 32) / 256);            // 80000 blocks
    dim3 ggrid(NN / 64);                    // 625 blocks

    // conv0: agg(x) -> P0 ; P1 = relu(P0@Wrel0 + x@Wroot0 + b0)
    hipMemsetAsync(P0, 0, hbytes, stream);
    scatter_kernel<<<sgrid, 256, 0, stream>>>(x, src, dst, P0);
    conv_gemm<true><<<ggrid, 256, 0, stream>>>(P0, x, Wrel[0], Wroot[0], bb[0], P1, NN);

    // conv1: agg(P1) -> P0 ; P2 = relu(...)
    hipMemsetAsync(P0, 0, hbytes, stream);
    scatter_kernel<<<sgrid, 256, 0, stream>>>(P1, src, dst, P0);
    conv_gemm<true><<<ggrid, 256, 0, stream>>>(P0, P1, Wrel[1], Wroot[1], bb[1], P2, NN);

    // conv2: agg(P2) -> P0 ; P1 = (no relu)
    hipMemsetAsync(P0, 0, hbytes, stream);
    scatter_kernel<<<sgrid, 256, 0, stream>>>(P2, src, dst, P0);
    conv_gemm<false><<<ggrid, 256, 0, stream>>>(P0, P2, Wrel[2], Wroot[2], bb[2], P1, NN);

    // fc0: P2 = relu(P1 @ Wfc0 + bfc0)   [NN x 64]
    fc0_kernel<<<dim3(NN / 16), 256, 0, stream>>>(P1, Wfc0, bfc0, P2);
    // fc1: out = P2 @ Wfc1 + bfc1        [NN x 1]
    fc1_kernel<<<dim3(NN / 4), 256, 0, stream>>>(P2, Wfc1, bfc1, out);
}

// Round 2
// 505.194 us; speedup vs baseline: 6.8238x; 6.8238x over previous
//
#include <hip/hip_runtime.h>

#define NN 40000
#define NE 640000
#define D  128
#define SEQ 40   // elements per thread in the 1024-thread scan (1024*40 >= NN)

// ---------------- CSR build ----------------
__global__ __launch_bounds__(256) void hist_kernel(
    const int* __restrict__ dst, int* __restrict__ counts)
{
    int e = blockIdx.x * 256 + threadIdx.x;
    if (e < NE) atomicAdd(&counts[dst[e]], 1);
}

// single block, 1024 threads: exclusive scan of counts -> cursor, inclusive -> row_ptr[1..]
__global__ __launch_bounds__(1024) void scan_kernel(
    const int* __restrict__ counts, int* __restrict__ row_ptr, int* __restrict__ cursor)
{
    __shared__ int buf[1024];
    const int tid = threadIdx.x;
    const int base = tid * SEQ;
    // local sum
    int s = 0;
    #pragma unroll 8
    for (int k = 0; k < SEQ; k++) {
        int idx = base + k;
        if (idx < NN) s += counts[idx];
    }
    buf[tid] = s;
    __syncthreads();
    // Hillis-Steele inclusive scan over 1024 partial sums
    for (int off = 1; off < 1024; off <<= 1) {
        int t = (tid >= off) ? buf[tid - off] : 0;
        __syncthreads();
        buf[tid] += t;
        __syncthreads();
    }
    int running = buf[tid] - s;   // exclusive prefix for this thread's chunk
    if (tid == 0) row_ptr[0] = 0;
    #pragma unroll 8
    for (int k = 0; k < SEQ; k++) {
        int idx = base + k;
        if (idx < NN) {
            cursor[idx] = running;
            running += counts[idx];
            row_ptr[idx + 1] = running;
        }
    }
}

__global__ __launch_bounds__(256) void fill_kernel(
    const int* __restrict__ src, const int* __restrict__ dst,
    int* __restrict__ cursor, int* __restrict__ src_sorted)
{
    int e = blockIdx.x * 256 + threadIdx.x;
    if (e >= NE) return;
    int d = dst[e];
    int pos = atomicAdd(&cursor[d], 1);
    src_sorted[pos] = src[e];
}

// ---------------- gather aggregation: agg[n] = sum_{e in CSR[n]} h[src_e] ----
__global__ __launch_bounds__(256) void gather_agg(
    const float* __restrict__ h, const int* __restrict__ row_ptr,
    const int* __restrict__ srcs, float* __restrict__ agg)
{
    int node = blockIdx.x * 8 + (threadIdx.x >> 5);   // 8 nodes per block, 32 lanes/node
    int lane = threadIdx.x & 31;
    if (node >= NN) return;
    int beg = row_ptr[node], end = row_ptr[node + 1];
    float4 acc = make_float4(0.f, 0.f, 0.f, 0.f);
    for (int e = beg; e < end; e++) {
        int s = srcs[e];
        float4 v = reinterpret_cast<const float4*>(h)[(size_t)s * 32 + lane];
        acc.x += v.x; acc.y += v.y; acc.z += v.z; acc.w += v.w;
    }
    reinterpret_cast<float4*>(agg)[(size_t)node * 32 + lane] = acc;
}

// ------- out = act(agg @ Wrel + h @ Wroot + b); M x 128, K = 128 ------------
template<bool RELU>
__global__ __launch_bounds__(256) void conv_gemm(
    const float* __restrict__ A,    // agg [M][128]
    const float* __restrict__ H,    // h   [M][128]
    const float* __restrict__ Wr,   // [128][128]
    const float* __restrict__ Wo,   // [128][128]
    const float* __restrict__ bias, // [128]
    float* __restrict__ out, int M)
{
    __shared__ float As[64][36];
    __shared__ float Hs[64][36];
    __shared__ float Wrs[32][128];
    __shared__ float Wos[32][128];

    const int tid  = threadIdx.x;
    const int row0 = blockIdx.x * 64;
    const int rg   = tid >> 4;   // 0..15 -> rows rg*4 .. rg*4+3
    const int cg   = tid & 15;   // 0..15 -> cols cg*8 .. cg*8+7

    float acc[4][8];
    #pragma unroll
    for (int i = 0; i < 4; i++)
        #pragma unroll
        for (int j = 0; j < 8; j++) acc[i][j] = 0.f;

    for (int k0 = 0; k0 < 128; k0 += 32) {
        #pragma unroll
        for (int l = 0; l < 2; l++) {
            int lin = tid + l * 256;
            int r   = lin >> 3;
            int f4  = lin & 7;
            float4 va = *reinterpret_cast<const float4*>(&A[(size_t)(row0 + r) * D + k0 + f4 * 4]);
            float4 vh = *reinterpret_cast<const float4*>(&H[(size_t)(row0 + r) * D + k0 + f4 * 4]);
            *reinterpret_cast<float4*>(&As[r][f4 * 4]) = va;
            *reinterpret_cast<float4*>(&Hs[r][f4 * 4]) = vh;
        }
        #pragma unroll
        for (int l = 0; l < 4; l++) {
            int lin = tid + l * 256;
            int kk  = lin >> 5;
            int f4  = lin & 31;
            *reinterpret_cast<float4*>(&Wrs[kk][f4 * 4]) =
                *reinterpret_cast<const float4*>(&Wr[(size_t)(k0 + kk) * D + f4 * 4]);
            *reinterpret_cast<float4*>(&Wos[kk][f4 * 4]) =
                *reinterpret_cast<const float4*>(&Wo[(size_t)(k0 + kk) * D + f4 * 4]);
        }
        __syncthreads();

        #pragma unroll 8
        for (int kk = 0; kk < 32; kk++) {
            float a[4], hh[4];
            #pragma unroll
            for (int i = 0; i < 4; i++) { a[i] = As[rg * 4 + i][kk]; hh[i] = Hs[rg * 4 + i][kk]; }
            float4 wr0 = *reinterpret_cast<float4*>(&Wrs[kk][cg * 8]);
            float4 wr1 = *reinterpret_cast<float4*>(&Wrs[kk][cg * 8 + 4]);
            float4 wo0 = *reinterpret_cast<float4*>(&Wos[kk][cg * 8]);
            float4 wo1 = *reinterpret_cast<float4*>(&Wos[kk][cg * 8 + 4]);
            float wr[8] = {wr0.x, wr0.y, wr0.z, wr0.w, wr1.x, wr1.y, wr1.z, wr1.w};
            float wo[8] = {wo0.x, wo0.y, wo0.z, wo0.w, wo1.x, wo1.y, wo1.z, wo1.w};
            #pragma unroll
            for (int i = 0; i < 4; i++)
                #pragma unroll
                for (int j = 0; j < 8; j++)
                    acc[i][j] += a[i] * wr[j] + hh[i] * wo[j];
        }
        __syncthreads();
    }

    #pragma unroll
    for (int i = 0; i < 4; i++) {
        int r = row0 + rg * 4 + i;
        float o[8];
        #pragma unroll
        for (int j = 0; j < 8; j++) {
            float v = acc[i][j] + bias[cg * 8 + j];
            if (RELU) v = fmaxf(v, 0.f);
            o[j] = v;
        }
        float4* dst4 = reinterpret_cast<float4*>(&out[(size_t)r * D + cg * 8]);
        dst4[0] = make_float4(o[0], o[1], o[2], o[3]);
        dst4[1] = make_float4(o[4], o[5], o[6], o[7]);
    }
}

// ---------------- fc0: out[NN][64] = relu(h[NN][128] @ W[128][64] + b) ------
__global__ __launch_bounds__(256) void fc0_kernel(
    const float* __restrict__ h, const float* __restrict__ W,
    const float* __restrict__ bias, float* __restrict__ out)
{
    __shared__ float Ws[128][64];
    __shared__ float Hs[16][128];
    const int tid = threadIdx.x;
    const float4* W4 = reinterpret_cast<const float4*>(W);
    float4* Ws4 = reinterpret_cast<float4*>(&Ws[0][0]);
    #pragma unroll
    for (int l = 0; l < 8; l++) Ws4[tid + l * 256] = W4[tid + l * 256];
    const int row0 = blockIdx.x * 16;
    const float4* h4 = reinterpret_cast<const float4*>(h + (size_t)row0 * 128);
    float4* Hs4 = reinterpret_cast<float4*>(&Hs[0][0]);
    #pragma unroll
    for (int l = 0; l < 2; l++) Hs4[tid + l * 256] = h4[tid + l * 256];
    __syncthreads();

    const int wv  = tid >> 6;
    const int col = tid & 63;
    float acc[4] = {bias[col], bias[col], bias[col], bias[col]};
    #pragma unroll 4
    for (int k = 0; k < 128; k++) {
        float w = Ws[k][col];
        #pragma unroll
        for (int j = 0; j < 4; j++) acc[j] += Hs[wv * 4 + j][k] * w;
    }
    #pragma unroll
    for (int j = 0; j < 4; j++)
        out[(size_t)(row0 + wv * 4 + j) * 64 + col] = fmaxf(acc[j], 0.f);
}

// ---------------- fc1: out[NN] = h[NN][64] @ W[64] + b ----------------------
__global__ __launch_bounds__(256) void fc1_kernel(
    const float* __restrict__ h, const float* __restrict__ W,
    const float* __restrict__ bias, float* __restrict__ out)
{
    int row  = blockIdx.x * 4 + (threadIdx.x >> 6);
    int lane = threadIdx.x & 63;
    float v = h[(size_t)row * 64 + lane] * W[lane];
    #pragma unroll
    for (int off = 32; off > 0; off >>= 1) v += __shfl_down(v, off, 64);
    if (lane == 0) out[row] = v + bias[0];
}

extern "C" void kernel_launch(void* const* d_in, const int* in_sizes, int n_in,
                              void* d_out, int out_size, void* d_ws, size_t ws_size,
                              hipStream_t stream)
{
    const float* x    = (const float*)d_in[0];
    const int*   ei   = (const int*)d_in[1];
    const int*   src  = ei;
    const int*   dst  = ei + NE;
    const float* Wrel[3]  = {(const float*)d_in[2], (const float*)d_in[5], (const float*)d_in[8]};
    const float* Wroot[3] = {(const float*)d_in[3], (const float*)d_in[6], (const float*)d_in[9]};
    const float* bb[3]    = {(const float*)d_in[4], (const float*)d_in[7], (const float*)d_in[10]};
    const float* Wfc0 = (const float*)d_in[11];
    const float* bfc0 = (const float*)d_in[12];
    const float* Wfc1 = (const float*)d_in[13];
    const float* bfc1 = (const float*)d_in[14];
    float* out = (float*)d_out;

    // workspace layout
    float* P0 = (float*)d_ws;                       // agg scratch [NN*D]
    float* P1 = P0 + (size_t)NN * D;                // hidden     [NN*D]
    float* P2 = P1 + (size_t)NN * D;                // hidden     [NN*D]
    int*   row_ptr    = (int*)(P2 + (size_t)NN * D);   // [NN+1]
    int*   cursor     = row_ptr + (NN + 1);            // [NN]
    int*   counts     = cursor + NN;                   // [NN]
    int*   src_sorted = counts + NN;                   // [NE]

    dim3 egrid((NE + 255) / 256);      // 2500 blocks (edge-parallel)
    dim3 agrid(NN / 8);                // 5000 blocks (8 nodes per block)
    dim3 ggrid(NN / 64);               // 625 blocks

    // ---- CSR build (once, reused by all 3 conv layers) ----
    hipMemsetAsync(counts, 0, NN * sizeof(int), stream);
    hist_kernel<<<egrid, 256, 0, stream>>>(dst, counts);
    scan_kernel<<<dim3(1), 1024, 0, stream>>>(counts, row_ptr, cursor);
    fill_kernel<<<egrid, 256, 0, stream>>>(src, dst, cursor, src_sorted);

    // conv0: agg(x) -> P0 ; P1 = relu(P0@Wrel0 + x@Wroot0 + b0)
    gather_agg<<<agrid, 256, 0, stream>>>(x, row_ptr, src_sorted, P0);
    conv_gemm<true><<<ggrid, 256, 0, stream>>>(P0, x, Wrel[0], Wroot[0], bb[0], P1, NN);

    // conv1
    gather_agg<<<agrid, 256, 0, stream>>>(P1, row_ptr, src_sorted, P0);
    conv_gemm<true><<<ggrid, 256, 0, stream>>>(P0, P1, Wrel[1], Wroot[1], bb[1], P2, NN);

    // conv2 (no relu)
    gather_agg<<<agrid, 256, 0, stream>>>(P2, row_ptr, src_sorted, P0);
    conv_gemm<false><<<ggrid, 256, 0, stream>>>(P0, P2, Wrel[2], Wroot[2], bb[2], P1, NN);

    // fc stack
    fc0_kernel<<<dim3(NN / 16), 256, 0, stream>>>(P1, Wfc0, bfc0, P2);
    fc1_kernel<<<dim3(NN / 4), 256, 0, stream>>>(P2, Wfc1, bfc1, out);
}

// Round 3
// 370.840 us; speedup vs baseline: 9.2960x; 1.3623x over previous
//
#include <hip/hip_runtime.h>
#include <hip/hip_bf16.h>

#define NN 40000
#define NE 640000
#define D  128
#define NBLK_SCAN ((NN + 255) / 256)   // 157

static __device__ inline unsigned short f2bf(float f) {
    __hip_bfloat16 h = __float2bfloat16(f);
    return *reinterpret_cast<unsigned short*>(&h);
}
static __device__ inline float bf_lo(unsigned int u) {  // element in low 16 bits
    unsigned int v = u << 16; return *reinterpret_cast<float*>(&v);
}
static __device__ inline float bf_hi(unsigned int u) {
    unsigned int v = u & 0xffff0000u; return *reinterpret_cast<float*>(&v);
}

// ---------------- CSR build ----------------
__global__ __launch_bounds__(256) void hist_kernel(
    const int* __restrict__ dst, int* __restrict__ counts)
{
    int e = blockIdx.x * 256 + threadIdx.x;
    if (e < NE) atomicAdd(&counts[dst[e]], 1);
}

__global__ __launch_bounds__(256) void blocksum_kernel(
    const int* __restrict__ counts, int* __restrict__ bsums)
{
    int i = blockIdx.x * 256 + threadIdx.x;
    int v = (i < NN) ? counts[i] : 0;
    #pragma unroll
    for (int off = 32; off > 0; off >>= 1) v += __shfl_down(v, off, 64);
    __shared__ int s[4];
    if ((threadIdx.x & 63) == 0) s[threadIdx.x >> 6] = v;
    __syncthreads();
    if (threadIdx.x == 0) bsums[blockIdx.x] = s[0] + s[1] + s[2] + s[3];
}

__global__ __launch_bounds__(256) void scan_bsums_kernel(
    const int* __restrict__ bsums, int* __restrict__ boffs, int* __restrict__ row_ptr)
{
    __shared__ int buf[256];
    int tid = threadIdx.x;
    int v = (tid < NBLK_SCAN) ? bsums[tid] : 0;
    buf[tid] = v;
    __syncthreads();
    for (int off = 1; off < 256; off <<= 1) {
        int t = (tid >= off) ? buf[tid - off] : 0;
        __syncthreads();
        buf[tid] += t;
        __syncthreads();
    }
    if (tid < NBLK_SCAN) boffs[tid] = buf[tid] - v;   // exclusive prefix
    if (tid == 0) row_ptr[0] = 0;
}

__global__ __launch_bounds__(256) void blockscan_kernel(
    const int* __restrict__ counts, const int* __restrict__ boffs,
    int* __restrict__ row_ptr, int* __restrict__ cursor)
{
    __shared__ int buf[256];
    int tid = threadIdx.x;
    int i = blockIdx.x * 256 + tid;
    int v = (i < NN) ? counts[i] : 0;
    buf[tid] = v;
    __syncthreads();
    for (int off = 1; off < 256; off <<= 1) {
        int t = (tid >= off) ? buf[tid - off] : 0;
        __syncthreads();
        buf[tid] += t;
        __syncthreads();
    }
    int inc = buf[tid] + boffs[blockIdx.x];
    if (i < NN) { row_ptr[i + 1] = inc; cursor[i] = inc - v; }
}

__global__ __launch_bounds__(256) void fill_kernel(
    const int* __restrict__ src, const int* __restrict__ dst,
    int* __restrict__ cursor, int* __restrict__ src_sorted)
{
    int e = blockIdx.x * 256 + threadIdx.x;
    if (e >= NE) return;
    int d = dst[e];
    int pos = atomicAdd(&cursor[d], 1);
    src_sorted[pos] = src[e];
}

// ---------------- convert f32 row-table to packed bf16 ----------------
__global__ __launch_bounds__(256) void convert_bf_kernel(
    const float* __restrict__ in, unsigned int* __restrict__ out4 /* uint4-packed */)
{
    int i = blockIdx.x * 256 + threadIdx.x;           // handles 8 floats
    const float4* in4 = reinterpret_cast<const float4*>(in);
    float4 a = in4[i * 2], b = in4[i * 2 + 1];
    uint4 u;
    u.x = f2bf(a.x) | (f2bf(a.y) << 16);
    u.y = f2bf(a.z) | (f2bf(a.w) << 16);
    u.z = f2bf(b.x) | (f2bf(b.y) << 16);
    u.w = f2bf(b.z) | (f2bf(b.w) << 16);
    reinterpret_cast<uint4*>(out4)[i] = u;
}

// ------- gather (bf16 rows): agg[n] = sum_e h_bf[src_e], f32 accumulate -----
__global__ __launch_bounds__(256) void gather_bf(
    const unsigned int* __restrict__ hbf,  // [NN][64] uints (128 bf16/row)
    const int* __restrict__ row_ptr, const int* __restrict__ srcs,
    float* __restrict__ agg)
{
    int node = blockIdx.x * 16 + (threadIdx.x >> 4);  // 16 nodes/block, 16 lanes/node
    int lane = threadIdx.x & 15;
    if (node >= NN) return;
    int beg = row_ptr[node], end = row_ptr[node + 1];
    float acc[8];
    #pragma unroll
    for (int j = 0; j < 8; j++) acc[j] = 0.f;
    const uint4* h4 = reinterpret_cast<const uint4*>(hbf);
    int e = beg;
    for (; e + 1 < end; e += 2) {                      // 2-way unroll for ILP
        int s0 = srcs[e], s1 = srcs[e + 1];
        uint4 u0 = h4[(size_t)s0 * 16 + lane];
        uint4 u1 = h4[(size_t)s1 * 16 + lane];
        acc[0] += bf_lo(u0.x); acc[1] += bf_hi(u0.x);
        acc[2] += bf_lo(u0.y); acc[3] += bf_hi(u0.y);
        acc[4] += bf_lo(u0.z); acc[5] += bf_hi(u0.z);
        acc[6] += bf_lo(u0.w); acc[7] += bf_hi(u0.w);
        acc[0] += bf_lo(u1.x); acc[1] += bf_hi(u1.x);
        acc[2] += bf_lo(u1.y); acc[3] += bf_hi(u1.y);
        acc[4] += bf_lo(u1.z); acc[5] += bf_hi(u1.z);
        acc[6] += bf_lo(u1.w); acc[7] += bf_hi(u1.w);
    }
    if (e < end) {
        uint4 u0 = h4[(size_t)srcs[e] * 16 + lane];
        acc[0] += bf_lo(u0.x); acc[1] += bf_hi(u0.x);
        acc[2] += bf_lo(u0.y); acc[3] += bf_hi(u0.y);
        acc[4] += bf_lo(u0.z); acc[5] += bf_hi(u0.z);
        acc[6] += bf_lo(u0.w); acc[7] += bf_hi(u0.w);
    }
    float4* o = reinterpret_cast<float4*>(&agg[(size_t)node * D + lane * 8]);
    o[0] = make_float4(acc[0], acc[1], acc[2], acc[3]);
    o[1] = make_float4(acc[4], acc[5], acc[6], acc[7]);
}

// ------- gather (f32 rows) — fallback when ws too small ----------------------
__global__ __launch_bounds__(256) void gather_agg(
    const float* __restrict__ h, const int* __restrict__ row_ptr,
    const int* __restrict__ srcs, float* __restrict__ agg)
{
    int node = blockIdx.x * 8 + (threadIdx.x >> 5);
    int lane = threadIdx.x & 31;
    if (node >= NN) return;
    int beg = row_ptr[node], end = row_ptr[node + 1];
    float4 acc = make_float4(0.f, 0.f, 0.f, 0.f);
    for (int e = beg; e < end; e++) {
        int s = srcs[e];
        float4 v = reinterpret_cast<const float4*>(h)[(size_t)s * 32 + lane];
        acc.x += v.x; acc.y += v.y; acc.z += v.z; acc.w += v.w;
    }
    reinterpret_cast<float4*>(agg)[(size_t)node * 32 + lane] = acc;
}

// ------- out = act(agg @ Wrel + h @ Wroot + b); M x 128, K = 128 ------------
template<bool RELU, bool WRITE_BF>
__global__ __launch_bounds__(256) void conv_gemm(
    const float* __restrict__ A,    // agg [M][128]
    const float* __restrict__ H,    // h   [M][128]
    const float* __restrict__ Wr,   // [128][128]
    const float* __restrict__ Wo,   // [128][128]
    const float* __restrict__ bias, // [128]
    float* __restrict__ out,
    unsigned int* __restrict__ out_bf, int M)
{
    __shared__ float As[64][36];
    __shared__ float Hs[64][36];
    __shared__ float Wrs[32][128];
    __shared__ float Wos[32][128];

    const int tid  = threadIdx.x;
    const int row0 = blockIdx.x * 64;
    const int rg   = tid >> 4;
    const int cg   = tid & 15;

    float acc[4][8];
    #pragma unroll
    for (int i = 0; i < 4; i++)
        #pragma unroll
        for (int j = 0; j < 8; j++) acc[i][j] = 0.f;

    for (int k0 = 0; k0 < 128; k0 += 32) {
        #pragma unroll
        for (int l = 0; l < 2; l++) {
            int lin = tid + l * 256;
            int r   = lin >> 3;
            int f4  = lin & 7;
            float4 va = *reinterpret_cast<const float4*>(&A[(size_t)(row0 + r) * D + k0 + f4 * 4]);
            float4 vh = *reinterpret_cast<const float4*>(&H[(size_t)(row0 + r) * D + k0 + f4 * 4]);
            *reinterpret_cast<float4*>(&As[r][f4 * 4]) = va;
            *reinterpret_cast<float4*>(&Hs[r][f4 * 4]) = vh;
        }
        #pragma unroll
        for (int l = 0; l < 4; l++) {
            int lin = tid + l * 256;
            int kk  = lin >> 5;
            int f4  = lin & 31;
            *reinterpret_cast<float4*>(&Wrs[kk][f4 * 4]) =
                *reinterpret_cast<const float4*>(&Wr[(size_t)(k0 + kk) * D + f4 * 4]);
            *reinterpret_cast<float4*>(&Wos[kk][f4 * 4]) =
                *reinterpret_cast<const float4*>(&Wo[(size_t)(k0 + kk) * D + f4 * 4]);
        }
        __syncthreads();

        #pragma unroll 8
        for (int kk = 0; kk < 32; kk++) {
            float a[4], hh[4];
            #pragma unroll
            for (int i = 0; i < 4; i++) { a[i] = As[rg * 4 + i][kk]; hh[i] = Hs[rg * 4 + i][kk]; }
            float4 wr0 = *reinterpret_cast<float4*>(&Wrs[kk][cg * 8]);
            float4 wr1 = *reinterpret_cast<float4*>(&Wrs[kk][cg * 8 + 4]);
            float4 wo0 = *reinterpret_cast<float4*>(&Wos[kk][cg * 8]);
            float4 wo1 = *reinterpret_cast<float4*>(&Wos[kk][cg * 8 + 4]);
            float wr[8] = {wr0.x, wr0.y, wr0.z, wr0.w, wr1.x, wr1.y, wr1.z, wr1.w};
            float wo[8] = {wo0.x, wo0.y, wo0.z, wo0.w, wo1.x, wo1.y, wo1.z, wo1.w};
            #pragma unroll
            for (int i = 0; i < 4; i++)
                #pragma unroll
                for (int j = 0; j < 8; j++)
                    acc[i][j] += a[i] * wr[j] + hh[i] * wo[j];
        }
        __syncthreads();
    }

    #pragma unroll
    for (int i = 0; i < 4; i++) {
        int r = row0 + rg * 4 + i;
        float o[8];
        #pragma unroll
        for (int j = 0; j < 8; j++) {
            float v = acc[i][j] + bias[cg * 8 + j];
            if (RELU) v = fmaxf(v, 0.f);
            o[j] = v;
        }
        float4* dst4 = reinterpret_cast<float4*>(&out[(size_t)r * D + cg * 8]);
        dst4[0] = make_float4(o[0], o[1], o[2], o[3]);
        dst4[1] = make_float4(o[4], o[5], o[6], o[7]);
        if (WRITE_BF) {
            uint4 u;
            u.x = f2bf(o[0]) | (f2bf(o[1]) << 16);
            u.y = f2bf(o[2]) | (f2bf(o[3]) << 16);
            u.z = f2bf(o[4]) | (f2bf(o[5]) << 16);
            u.w = f2bf(o[6]) | (f2bf(o[7]) << 16);
            reinterpret_cast<uint4*>(out_bf)[(size_t)r * 16 + cg] = u;
        }
    }
}

// ---------------- fc0: out[NN][64] = relu(h[NN][128] @ W[128][64] + b) ------
__global__ __launch_bounds__(256) void fc0_kernel(
    const float* __restrict__ h, const float* __restrict__ W,
    const float* __restrict__ bias, float* __restrict__ out)
{
    __shared__ float Ws[128][64];
    __shared__ float Hs[16][128];
    const int tid = threadIdx.x;
    const float4* W4 = reinterpret_cast<const float4*>(W);
    float4* Ws4 = reinterpret_cast<float4*>(&Ws[0][0]);
    #pragma unroll
    for (int l = 0; l < 8; l++) Ws4[tid + l * 256] = W4[tid + l * 256];
    const int row0 = blockIdx.x * 16;
    const float4* h4 = reinterpret_cast<const float4*>(h + (size_t)row0 * 128);
    float4* Hs4 = reinterpret_cast<float4*>(&Hs[0][0]);
    #pragma unroll
    for (int l = 0; l < 2; l++) Hs4[tid + l * 256] = h4[tid + l * 256];
    __syncthreads();

    const int wv  = tid >> 6;
    const int col = tid & 63;
    float acc[4] = {bias[col], bias[col], bias[col], bias[col]};
    #pragma unroll 4
    for (int k = 0; k < 128; k++) {
        float w = Ws[k][col];
        #pragma unroll
        for (int j = 0; j < 4; j++) acc[j] += Hs[wv * 4 + j][k] * w;
    }
    #pragma unroll
    for (int j = 0; j < 4; j++)
        out[(size_t)(row0 + wv * 4 + j) * 64 + col] = fmaxf(acc[j], 0.f);
}

// ---------------- fc1: out[NN] = h[NN][64] @ W[64] + b ----------------------
__global__ __launch_bounds__(256) void fc1_kernel(
    const float* __restrict__ h, const float* __restrict__ W,
    const float* __restrict__ bias, float* __restrict__ out)
{
    int row  = blockIdx.x * 4 + (threadIdx.x >> 6);
    int lane = threadIdx.x & 63;
    float v = h[(size_t)row * 64 + lane] * W[lane];
    #pragma unroll
    for (int off = 32; off > 0; off >>= 1) v += __shfl_down(v, off, 64);
    if (lane == 0) out[row] = v + bias[0];
}

extern "C" void kernel_launch(void* const* d_in, const int* in_sizes, int n_in,
                              void* d_out, int out_size, void* d_ws, size_t ws_size,
                              hipStream_t stream)
{
    const float* x    = (const float*)d_in[0];
    const int*   ei   = (const int*)d_in[1];
    const int*   src  = ei;
    const int*   dst  = ei + NE;
    const float* Wrel[3]  = {(const float*)d_in[2], (const float*)d_in[5], (const float*)d_in[8]};
    const float* Wroot[3] = {(const float*)d_in[3], (const float*)d_in[6], (const float*)d_in[9]};
    const float* bb[3]    = {(const float*)d_in[4], (const float*)d_in[7], (const float*)d_in[10]};
    const float* Wfc0 = (const float*)d_in[11];
    const float* bfc0 = (const float*)d_in[12];
    const float* Wfc1 = (const float*)d_in[13];
    const float* bfc1 = (const float*)d_in[14];
    float* out = (float*)d_out;

    // ---- workspace layout ----
    float* P0 = (float*)d_ws;                          // agg scratch [NN*D] f32
    float* P1 = P0 + (size_t)NN * D;
    float* P2 = P1 + (size_t)NN * D;
    int*   row_ptr    = (int*)(P2 + (size_t)NN * D);   // [NN+1]
    int*   cursor     = row_ptr + (NN + 1);            // [NN]
    int*   counts     = cursor + NN;                   // [NN]
    int*   bsums      = counts + NN;                   // [256]
    int*   boffs      = bsums + 256;                   // [256]
    int*   src_sorted = boffs + 256;                   // [NE]
    unsigned int* BF0 = (unsigned int*)(src_sorted + NE);     // [NN*64] packed bf16
    unsigned int* BF1 = BF0 + (size_t)NN * 64;
    const size_t needed = (size_t)((char*)(BF1 + (size_t)NN * 64) - (char*)d_ws);
    const bool use_bf = (ws_size >= needed);

    dim3 egrid((NE + 255) / 256);      // 2500
    dim3 ggrid(NN / 64);               // 625

    // ---- CSR build ----
    hipMemsetAsync(counts, 0, NN * sizeof(int), stream);
    hist_kernel<<<egrid, 256, 0, stream>>>(dst, counts);
    blocksum_kernel<<<dim3(NBLK_SCAN), 256, 0, stream>>>(counts, bsums);
    scan_bsums_kernel<<<dim3(1), 256, 0, stream>>>(bsums, boffs, row_ptr);
    blockscan_kernel<<<dim3(NBLK_SCAN), 256, 0, stream>>>(counts, boffs, row_ptr, cursor);
    fill_kernel<<<egrid, 256, 0, stream>>>(src, dst, cursor, src_sorted);

    if (use_bf) {
        // conv0
        convert_bf_kernel<<<dim3(NN * D / 8 / 256), 256, 0, stream>>>(x, BF0);
        gather_bf<<<dim3(NN / 16), 256, 0, stream>>>(BF0, row_ptr, src_sorted, P0);
        conv_gemm<true, true><<<ggrid, 256, 0, stream>>>(P0, x, Wrel[0], Wroot[0], bb[0], P1, BF1, NN);
        // conv1
        gather_bf<<<dim3(NN / 16), 256, 0, stream>>>(BF1, row_ptr, src_sorted, P0);
        conv_gemm<true, true><<<ggrid, 256, 0, stream>>>(P0, P1, Wrel[1], Wroot[1], bb[1], P2, BF0, NN);
        // conv2 (no relu, no bf copy)
        gather_bf<<<dim3(NN / 16), 256, 0, stream>>>(BF0, row_ptr, src_sorted, P0);
        conv_gemm<false, false><<<ggrid, 256, 0, stream>>>(P0, P2, Wrel[2], Wroot[2], bb[2], P1, nullptr, NN);
    } else {
        gather_agg<<<dim3(NN / 8), 256, 0, stream>>>(x, row_ptr, src_sorted, P0);
        conv_gemm<true, false><<<ggrid, 256, 0, stream>>>(P0, x, Wrel[0], Wroot[0], bb[0], P1, nullptr, NN);
        gather_agg<<<dim3(NN / 8), 256, 0, stream>>>(P1, row_ptr, src_sorted, P0);
        conv_gemm<true, false><<<ggrid, 256, 0, stream>>>(P0, P1, Wrel[1], Wroot[1], bb[1], P2, nullptr, NN);
        gather_agg<<<dim3(NN / 8), 256, 0, stream>>>(P2, row_ptr, src_sorted, P0);
        conv_gemm<false, false><<<ggrid, 256, 0, stream>>>(P0, P2, Wrel[2], Wroot[2], bb[2], P1, nullptr, NN);
    }

    // fc stack
    fc0_kernel<<<dim3(NN / 16), 256, 0, stream>>>(P1, Wfc0, bfc0, P2);
    fc1_kernel<<<dim3(NN / 4), 256, 0, stream>>>(P2, Wfc1, bfc1, out);
}